// Round 6
// baseline (65.872 us; speedup 1.0000x reference)
//
#include <hip/hip_runtime.h>

// ConvSSM scan, spatial domain, step-doubled, 1024-thread scan (4 waves/SIMD).
//   h_t = A (*) h_{t-1} + u_t,  u_t = B (*) xpad_t,  (*) = circular conv on 64x64.
// H_m = h_{2m+1}:
//   H_m  = A2 (*) H_{m-1} + G_m,  A2 = A(*)A (5x5),  G_m = A(*)u_{2m} + u_{2m+1}
//   h_2m = A  (*) H_{m-1} + u_{2m}   (even emit, crop region only)
// Pass 1 (2048 blocks, vectorized): U_m = u_{2m} crop 32x32, G_m (36x36) -> d_ws.
// Pass 2 (64 blocks x 1024 thr): 32-step scan, h in LDS dbuf, 1x4 tile/thread,
//   own-row accumulator kept in registers, A/A2 in SGPRs via readfirstlane.

constexpr int T_STEPS = 64;
constexpr int B_DIM   = 2;
constexpr int C_DIM   = 32;
constexpr int HW      = 32;
constexpr int N       = 64;
constexpr int NIMG    = B_DIM * C_DIM;   // 64
constexpr int MH      = T_STEPS / 2;     // 32 scan steps
constexpr int HSTR    = 68;              // LDS row stride (floats)
constexpr int GSZ     = 36 * 36;         // 1296 floats
constexpr int USZ     = HW * HW;         // 1024 floats (cropped u_even)

__device__ __forceinline__ float rfl(float v) {
    return __int_as_float(__builtin_amdgcn_readfirstlane(__float_as_int(v)));
}

// ---------------- Pass 1: U_m (32x32), G_m (36x36) per (m, bc) ---------------
__global__ __launch_bounds__(256)
void convssm_pass1d(const float* __restrict__ x_seq,  // (T,B,C,32,32)
                    const float* __restrict__ A_k,    // (C,3,3)
                    const float* __restrict__ B_k,    // (C,3,3)
                    float* __restrict__ U,            // (NIMG*MH, 32, 32) idx bc*MH+m
                    float* __restrict__ G)            // (NIMG*MH, 36, 36)
{
    __shared__ __align__(16) float xe[32][36];
    __shared__ __align__(16) float xo[32][36];
    __shared__ __align__(16) float ue[34][36];

    const int blk = blockIdx.x;           // m*64 + bc
    const int m   = blk >> 6;
    const int bc  = blk & 63;
    const int c   = bc & 31;
    const int tid = threadIdx.x;

    float a[9], bw[9];
#pragma unroll
    for (int i = 0; i < 9; ++i) { a[i] = A_k[c * 9 + i]; bw[i] = B_k[c * 9 + i]; }

    const float4* xE = (const float4*)(x_seq + ((size_t)(2 * m)     * NIMG + bc) * (HW * HW));
    const float4* xO = (const float4*)(x_seq + ((size_t)(2 * m + 1) * NIMG + bc) * (HW * HW));
    {
        const int y  = tid >> 3;          // 0..31
        const int x4 = (tid & 7) * 4;     // 0,4,...,28
        *(float4*)&xe[y][x4] = xE[tid];
        *(float4*)&xo[y][x4] = xO[tid];
    }
    __syncthreads();

    // ue = B (*) xpad_{2m} over 34x34
    for (int i = tid; i < 34 * 34; i += 256) {
        int y = i / 34, xx = i - y * 34;
        float v = 0.0f;
#pragma unroll
        for (int ky = 0; ky < 3; ++ky) {
            int yy = y - ky;
            if (yy < 0 || yy >= 32) continue;
#pragma unroll
            for (int kx = 0; kx < 3; ++kx) {
                int xs = xx - kx;
                if (xs < 0 || xs >= 32) continue;
                v += bw[ky * 3 + kx] * xe[yy][xs];
            }
        }
        ue[y][xx] = v;
    }
    __syncthreads();

    // store U = crop(ue) as float4
    float* Ug = U + (size_t)(bc * MH + m) * USZ;
    {
        const int y  = tid >> 3;
        const int x4 = (tid & 7) * 4;
        *(float4*)(Ug + y * HW + x4) = *(const float4*)&ue[y][x4];
    }

    // G_m = B (*) xpad_{2m+1} + A (*) ue : support 36x36, stored as float4
    float* Gg = G + (size_t)(bc * MH + m) * GSZ;
    for (int i4 = tid; i4 < 324; i4 += 256) {
        const int y  = i4 / 9;
        const int x0 = (i4 - y * 9) * 4;
        float r[4];
#pragma unroll
        for (int j = 0; j < 4; ++j) {
            const int xx = x0 + j;
            float v = 0.0f;
#pragma unroll
            for (int ky = 0; ky < 3; ++ky) {
#pragma unroll
                for (int kx = 0; kx < 3; ++kx) {
                    int yy = y - ky, xs = xx - kx;
                    if (yy >= 0 && yy < 32 && xs >= 0 && xs < 32)
                        v += bw[ky * 3 + kx] * xo[yy][xs];
                    if (yy >= 0 && yy < 34 && xs >= 0 && xs < 34)
                        v += a[ky * 3 + kx] * ue[yy][xs];
                }
            }
            r[j] = v;
        }
        *(float4*)(Gg + y * 36 + x0) = make_float4(r[0], r[1], r[2], r[3]);
    }
}

// ---------------- Pass 2: 32-step scan, 1024 threads -------------------------
__global__ __launch_bounds__(1024)
void convssm_scan5(const float* __restrict__ U,
                   const float* __restrict__ G,
                   const float* __restrict__ A_k,
                   float* __restrict__ out)          // (T,B,C,32,32)
{
    __shared__ __align__(16) float hbuf[2][N * HSTR];

    const int bc  = blockIdx.x;          // 0..63
    const int c   = bc & 31;
    const int tid = threadIdx.x;
    const int g   = tid & 15;            // col group: cols 4g..4g+3
    const int y   = tid >> 4;            // 0..63: own row
    const int xc  = g * 4;
    const int xlo = (xc + 60) & 63;      // xc-4 mod 64

    // A, A2 -> compute in VALU, park in SGPRs (block-uniform)
    float af[9];
#pragma unroll
    for (int i = 0; i < 9; ++i) af[i] = A_k[c * 9 + i];

    float a2f[25];
#pragma unroll
    for (int p = 0; p < 5; ++p) {
#pragma unroll
        for (int q = 0; q < 5; ++q) {
            float v = 0.0f;
#pragma unroll
            for (int ky = 0; ky < 3; ++ky) {
                int py = p - ky;
                if (py < 0 || py > 2) continue;
#pragma unroll
                for (int kx = 0; kx < 3; ++kx) {
                    int qx = q - kx;
                    if (qx < 0 || qx > 2) continue;
                    v += af[ky * 3 + kx] * af[py * 3 + qx];
                }
            }
            a2f[p * 5 + q] = v;
        }
    }
#pragma unroll
    for (int i = 0; i < 25; ++i) a2f[i] = rfl(a2f[i]);
#pragma unroll
    for (int i = 0; i < 9; ++i)  af[i]  = rfl(af[i]);

    for (int i = tid; i < N * HSTR; i += 1024) hbuf[0][i] = 0.0f;

    const bool cropw = (y < HW);                 // wave-uniform (4 consecutive rows)
    const bool crop  = cropw && (xc < HW);
    const bool gok   = (y < 36) && (xc <= 32);

    const float* Ub = U + (size_t)bc * MH * USZ + y * HW + xc;
    const float* Gb = G + (size_t)bc * MH * GSZ + y * 36 + xc;

    const float4 z4 = make_float4(0.f, 0.f, 0.f, 0.f);
    float4 gc = z4, uc = z4;
    if (gok)  gc = *(const float4*)(Gb);
    if (crop) uc = *(const float4*)(Ub);

    float* hold = &hbuf[0][0];
    float* hnew = &hbuf[1][0];
    float* ob   = out + (size_t)bc * (HW * HW);
    const size_t tstr = (size_t)NIMG * (HW * HW);  // 65536

    float4 acc = z4;   // own row y, cols xc..xc+3 of h_old (starts at 0)

    __syncthreads();

    for (int m = 0; m < MH; ++m) {
        // prefetch next step's G / U
        float4 gn = z4, un = z4;
        if (m + 1 < MH) {
            if (gok)  gn = *(const float4*)(Gb + (size_t)(m + 1) * GSZ);
            if (crop) un = *(const float4*)(Ub + (size_t)(m + 1) * USZ);
        }

        // 5x8 window: rows y-4..y, cols xc-4..xc+3; own row hi-half = acc (regs)
        float w[5][8];
#pragma unroll
        for (int i = 0; i < 5; ++i) {
            const int rr = (y + 60 + i) & 63;
            const float4 lo = *(const float4*)(hold + rr * HSTR + xlo);
            w[i][0] = lo.x; w[i][1] = lo.y; w[i][2] = lo.z; w[i][3] = lo.w;
            if (i < 4) {
                const float4 hi = *(const float4*)(hold + rr * HSTR + xc);
                w[i][4] = hi.x; w[i][5] = hi.y; w[i][6] = hi.z; w[i][7] = hi.w;
            }
        }
        w[4][4] = acc.x; w[4][5] = acc.y; w[4][6] = acc.z; w[4][7] = acc.w;

        // H_new = A2 (*) H_old + G   (1 row x 4 cols)
        float o[4] = { gc.x, gc.y, gc.z, gc.w };
#pragma unroll
        for (int p = 0; p < 5; ++p) {
            const int i = 4 - p;
#pragma unroll
            for (int q = 0; q < 5; ++q) {
                const float cf = a2f[p * 5 + q];
#pragma unroll
                for (int j = 0; j < 4; ++j)
                    o[j] += cf * w[i][4 + j - q];
            }
        }
        const float4 accn = make_float4(o[0], o[1], o[2], o[3]);

        // even emit: h_{2m} = A (*) H_old + u_{2m}
        if (cropw) {
            float e[4] = { uc.x, uc.y, uc.z, uc.w };
#pragma unroll
            for (int ky = 0; ky < 3; ++ky) {
                const int i = 4 - ky;
#pragma unroll
                for (int kx = 0; kx < 3; ++kx) {
                    const float cf = af[ky * 3 + kx];
#pragma unroll
                    for (int j = 0; j < 4; ++j)
                        e[j] += cf * w[i][4 + j - kx];
                }
            }
            if (crop) {
                float* oe = ob + (size_t)(2 * m) * tstr;
                *(float4*)(oe + y * HW + xc) = make_float4(e[0], e[1], e[2], e[3]);
                *(float4*)(oe + tstr + y * HW + xc) = accn;
            }
        }

        *(float4*)(hnew + y * HSTR + xc) = accn;

        __syncthreads();   // hnew complete; all reads of hold done

        float* tmp = hold; hold = hnew; hnew = tmp;
        acc = accn;
        gc = gn; uc = un;
    }
}

// ---------------- Fallback (round-1 fused, known-correct) --------------------
__global__ __launch_bounds__(256)
void convssm_scan_fused(const float* __restrict__ x_seq,
                        const float* __restrict__ A_k,
                        const float* __restrict__ B_k,
                        float* __restrict__ out)
{
    __shared__ float h0[N][N];
    __shared__ float h1[N][N];
    __shared__ float xs[N][N];

    const int bc = blockIdx.x;
    const int b  = bc >> 5;
    const int c  = bc & 31;
    const int tid = threadIdx.x;
    const int x   = tid & 63;
    const int y0  = (tid >> 6) << 4;

    float a[9], bw[9];
#pragma unroll
    for (int i = 0; i < 9; ++i) { a[i] = A_k[c*9+i]; bw[i] = B_k[c*9+i]; }
#pragma unroll
    for (int r = 0; r < 16; ++r) { h0[y0+r][x] = 0.f; xs[y0+r][x] = 0.f; }

    float (*hold)[N] = h0;
    float (*hnew)[N] = h1;
    const int xm1 = (x + 63) & 63, xm2 = (x + 62) & 63;
    const size_t img = (size_t)HW*HW, tstr = (size_t)NIMG*img;
    const float* xbase = x_seq + ((size_t)b*C_DIM + c)*img;
    float* obase = out + ((size_t)b*C_DIM + c)*img;
    const bool loader = (x < HW);

    for (int t = 0; t < T_STEPS; ++t) {
        if (loader) {
#pragma unroll
            for (int r = 0; r < 16; ++r) {
                int yy = y0 + r;
                if (yy < HW) xs[yy][x] = xbase[(size_t)t*tstr + yy*HW + x];
            }
        }
        __syncthreads();
        const int ym1 = (y0 + N - 1) & 63, ym2 = (y0 + N - 2) & 63;
        float hr1c0 = hold[ym1][x], hr1c1 = hold[ym1][xm1], hr1c2 = hold[ym1][xm2];
        float hr2c0 = hold[ym2][x], hr2c1 = hold[ym2][xm1], hr2c2 = hold[ym2][xm2];
        float sr1c0 = xs[ym1][x], sr1c1 = xs[ym1][xm1], sr1c2 = xs[ym1][xm2];
        float sr2c0 = xs[ym2][x], sr2c1 = xs[ym2][xm1], sr2c2 = xs[ym2][xm2];
#pragma unroll
        for (int r = 0; r < 16; ++r) {
            const int yy = y0 + r;
            float hr0c0 = hold[yy][x], hr0c1 = hold[yy][xm1], hr0c2 = hold[yy][xm2];
            float sr0c0 = xs[yy][x], sr0c1 = xs[yy][xm1], sr0c2 = xs[yy][xm2];
            float v = a[0]*hr0c0 + a[1]*hr0c1 + a[2]*hr0c2
                    + a[3]*hr1c0 + a[4]*hr1c1 + a[5]*hr1c2
                    + a[6]*hr2c0 + a[7]*hr2c1 + a[8]*hr2c2
                    + bw[0]*sr0c0 + bw[1]*sr0c1 + bw[2]*sr0c2
                    + bw[3]*sr1c0 + bw[4]*sr1c1 + bw[5]*sr1c2
                    + bw[6]*sr2c0 + bw[7]*sr2c1 + bw[8]*sr2c2;
            hnew[yy][x] = v;
            if (yy < HW && x < HW) obase[(size_t)t*tstr + yy*HW + x] = v;
            hr2c0=hr1c0; hr2c1=hr1c1; hr2c2=hr1c2;
            hr1c0=hr0c0; hr1c1=hr0c1; hr1c2=hr0c2;
            sr2c0=sr1c0; sr2c1=sr1c1; sr2c2=sr1c2;
            sr1c0=sr0c0; sr1c1=sr0c1; sr1c2=sr0c2;
        }
        __syncthreads();
        float (*tmp)[N] = hold; hold = hnew; hnew = tmp;
    }
}

extern "C" void kernel_launch(void* const* d_in, const int* in_sizes, int n_in,
                              void* d_out, int out_size, void* d_ws, size_t ws_size,
                              hipStream_t stream)
{
    const float* x_seq = (const float*)d_in[0];
    const float* A_k   = (const float*)d_in[1];
    const float* B_k   = (const float*)d_in[2];
    float* out = (float*)d_out;

    const size_t needU = (size_t)NIMG * MH * USZ;             // floats
    const size_t needG = (size_t)NIMG * MH * GSZ;
    const size_t need  = (needU + needG) * sizeof(float);     // ~19 MB

    if (ws_size >= need) {
        float* U = (float*)d_ws;
        float* G = U + needU;
        convssm_pass1d<<<dim3(MH * NIMG), dim3(256), 0, stream>>>(
            x_seq, A_k, B_k, U, G);
        convssm_scan5<<<dim3(NIMG), dim3(1024), 0, stream>>>(
            U, G, A_k, out);
    } else {
        convssm_scan_fused<<<dim3(NIMG), dim3(256), 0, stream>>>(
            x_seq, A_k, B_k, out);
    }
}

// Round 7
// 65.791 us; speedup vs baseline: 1.0012x; 1.0012x over previous
//
#include <hip/hip_runtime.h>

// ConvSSM scan, spatial domain, step-doubled, 1024-thread scan (4 waves/SIMD).
//   h_t = A (*) h_{t-1} + u_t,  u_t = B (*) xpad_t,  (*) = circular conv on 64x64.
// H_m = h_{2m+1}:
//   H_m  = A2 (*) H_{m-1} + G_m,  A2 = A(*)A (5x5),  G_m = A(*)u_{2m} + u_{2m+1}
//   h_2m = A  (*) H_{m-1} + u_{2m}   (even emit, crop region only)
// Pass 1 (2048 blocks, vectorized): U_m = u_{2m} crop 32x32, G_m (36x36) -> d_ws.
// Pass 2 (64 blocks x 1024 thr): 32-step scan, h in LDS dbuf, 1x4 tile/thread,
//   own-row accumulator kept in registers, A/A2 in SGPRs via readfirstlane.

constexpr int T_STEPS = 64;
constexpr int B_DIM   = 2;
constexpr int C_DIM   = 32;
constexpr int HW      = 32;
constexpr int N       = 64;
constexpr int NIMG    = B_DIM * C_DIM;   // 64
constexpr int MH      = T_STEPS / 2;     // 32 scan steps
constexpr int HSTR    = 68;              // LDS row stride (floats)
constexpr int GSZ     = 36 * 36;         // 1296 floats
constexpr int USZ     = HW * HW;         // 1024 floats (cropped u_even)

__device__ __forceinline__ float rfl(float v) {
    return __int_as_float(__builtin_amdgcn_readfirstlane(__float_as_int(v)));
}

// ---------------- Pass 1: U_m (32x32), G_m (36x36) per (m, bc) ---------------
__global__ __launch_bounds__(256)
void convssm_pass1d(const float* __restrict__ x_seq,  // (T,B,C,32,32)
                    const float* __restrict__ A_k,    // (C,3,3)
                    const float* __restrict__ B_k,    // (C,3,3)
                    float* __restrict__ U,            // (NIMG*MH, 32, 32) idx bc*MH+m
                    float* __restrict__ G)            // (NIMG*MH, 36, 36)
{
    __shared__ __align__(16) float xe[32][36];
    __shared__ __align__(16) float xo[32][36];
    __shared__ __align__(16) float ue[34][36];

    const int blk = blockIdx.x;           // m*64 + bc
    const int m   = blk >> 6;
    const int bc  = blk & 63;
    const int c   = bc & 31;
    const int tid = threadIdx.x;

    float a[9], bw[9];
#pragma unroll
    for (int i = 0; i < 9; ++i) { a[i] = A_k[c * 9 + i]; bw[i] = B_k[c * 9 + i]; }

    const float4* xE = (const float4*)(x_seq + ((size_t)(2 * m)     * NIMG + bc) * (HW * HW));
    const float4* xO = (const float4*)(x_seq + ((size_t)(2 * m + 1) * NIMG + bc) * (HW * HW));
    {
        const int y  = tid >> 3;          // 0..31
        const int x4 = (tid & 7) * 4;     // 0,4,...,28
        *(float4*)&xe[y][x4] = xE[tid];
        *(float4*)&xo[y][x4] = xO[tid];
    }
    __syncthreads();

    // ue = B (*) xpad_{2m} over 34x34
    for (int i = tid; i < 34 * 34; i += 256) {
        int y = i / 34, xx = i - y * 34;
        float v = 0.0f;
#pragma unroll
        for (int ky = 0; ky < 3; ++ky) {
            int yy = y - ky;
            if (yy < 0 || yy >= 32) continue;
#pragma unroll
            for (int kx = 0; kx < 3; ++kx) {
                int xs = xx - kx;
                if (xs < 0 || xs >= 32) continue;
                v += bw[ky * 3 + kx] * xe[yy][xs];
            }
        }
        ue[y][xx] = v;
    }
    __syncthreads();

    // store U = crop(ue) as float4
    float* Ug = U + (size_t)(bc * MH + m) * USZ;
    {
        const int y  = tid >> 3;
        const int x4 = (tid & 7) * 4;
        *(float4*)(Ug + y * HW + x4) = *(const float4*)&ue[y][x4];
    }

    // G_m = B (*) xpad_{2m+1} + A (*) ue : support 36x36, stored as float4
    float* Gg = G + (size_t)(bc * MH + m) * GSZ;
    for (int i4 = tid; i4 < 324; i4 += 256) {
        const int y  = i4 / 9;
        const int x0 = (i4 - y * 9) * 4;
        float r[4];
#pragma unroll
        for (int j = 0; j < 4; ++j) {
            const int xx = x0 + j;
            float v = 0.0f;
#pragma unroll
            for (int ky = 0; ky < 3; ++ky) {
#pragma unroll
                for (int kx = 0; kx < 3; ++kx) {
                    int yy = y - ky, xs = xx - kx;
                    if (yy >= 0 && yy < 32 && xs >= 0 && xs < 32)
                        v += bw[ky * 3 + kx] * xo[yy][xs];
                    if (yy >= 0 && yy < 34 && xs >= 0 && xs < 34)
                        v += a[ky * 3 + kx] * ue[yy][xs];
                }
            }
            r[j] = v;
        }
        *(float4*)(Gg + y * 36 + x0) = make_float4(r[0], r[1], r[2], r[3]);
    }
}

// ---------------- Pass 2: 32-step scan, 1024 threads -------------------------
__global__ __launch_bounds__(1024)
void convssm_scan5(const float* __restrict__ U,
                   const float* __restrict__ G,
                   const float* __restrict__ A_k,
                   float* __restrict__ out)          // (T,B,C,32,32)
{
    __shared__ __align__(16) float hbuf[2][N * HSTR];

    const int bc  = blockIdx.x;          // 0..63
    const int c   = bc & 31;
    const int tid = threadIdx.x;
    const int g   = tid & 15;            // col group: cols 4g..4g+3
    const int y   = tid >> 4;            // 0..63: own row
    const int xc  = g * 4;
    const int xlo = (xc + 60) & 63;      // xc-4 mod 64

    // A, A2 -> compute in VALU, park in SGPRs (block-uniform)
    float af[9];
#pragma unroll
    for (int i = 0; i < 9; ++i) af[i] = A_k[c * 9 + i];

    float a2f[25];
#pragma unroll
    for (int p = 0; p < 5; ++p) {
#pragma unroll
        for (int q = 0; q < 5; ++q) {
            float v = 0.0f;
#pragma unroll
            for (int ky = 0; ky < 3; ++ky) {
                int py = p - ky;
                if (py < 0 || py > 2) continue;
#pragma unroll
                for (int kx = 0; kx < 3; ++kx) {
                    int qx = q - kx;
                    if (qx < 0 || qx > 2) continue;
                    v += af[ky * 3 + kx] * af[py * 3 + qx];
                }
            }
            a2f[p * 5 + q] = v;
        }
    }
#pragma unroll
    for (int i = 0; i < 25; ++i) a2f[i] = rfl(a2f[i]);
#pragma unroll
    for (int i = 0; i < 9; ++i)  af[i]  = rfl(af[i]);

    for (int i = tid; i < N * HSTR; i += 1024) hbuf[0][i] = 0.0f;

    const bool cropw = (y < HW);                 // wave-uniform (4 consecutive rows)
    const bool crop  = cropw && (xc < HW);
    const bool gok   = (y < 36) && (xc <= 32);

    const float* Ub = U + (size_t)bc * MH * USZ + y * HW + xc;
    const float* Gb = G + (size_t)bc * MH * GSZ + y * 36 + xc;

    const float4 z4 = make_float4(0.f, 0.f, 0.f, 0.f);
    float4 gc = z4, uc = z4;
    if (gok)  gc = *(const float4*)(Gb);
    if (crop) uc = *(const float4*)(Ub);

    float* hold = &hbuf[0][0];
    float* hnew = &hbuf[1][0];
    float* ob   = out + (size_t)bc * (HW * HW);
    const size_t tstr = (size_t)NIMG * (HW * HW);  // 65536

    float4 acc = z4;   // own row y, cols xc..xc+3 of h_old (starts at 0)

    __syncthreads();

    for (int m = 0; m < MH; ++m) {
        // prefetch next step's G / U
        float4 gn = z4, un = z4;
        if (m + 1 < MH) {
            if (gok)  gn = *(const float4*)(Gb + (size_t)(m + 1) * GSZ);
            if (crop) un = *(const float4*)(Ub + (size_t)(m + 1) * USZ);
        }

        // 5x8 window: rows y-4..y, cols xc-4..xc+3; own row hi-half = acc (regs)
        float w[5][8];
#pragma unroll
        for (int i = 0; i < 5; ++i) {
            const int rr = (y + 60 + i) & 63;
            const float4 lo = *(const float4*)(hold + rr * HSTR + xlo);
            w[i][0] = lo.x; w[i][1] = lo.y; w[i][2] = lo.z; w[i][3] = lo.w;
            if (i < 4) {
                const float4 hi = *(const float4*)(hold + rr * HSTR + xc);
                w[i][4] = hi.x; w[i][5] = hi.y; w[i][6] = hi.z; w[i][7] = hi.w;
            }
        }
        w[4][4] = acc.x; w[4][5] = acc.y; w[4][6] = acc.z; w[4][7] = acc.w;

        // H_new = A2 (*) H_old + G   (1 row x 4 cols)
        float o[4] = { gc.x, gc.y, gc.z, gc.w };
#pragma unroll
        for (int p = 0; p < 5; ++p) {
            const int i = 4 - p;
#pragma unroll
            for (int q = 0; q < 5; ++q) {
                const float cf = a2f[p * 5 + q];
#pragma unroll
                for (int j = 0; j < 4; ++j)
                    o[j] += cf * w[i][4 + j - q];
            }
        }
        const float4 accn = make_float4(o[0], o[1], o[2], o[3]);

        // even emit: h_{2m} = A (*) H_old + u_{2m}
        if (cropw) {
            float e[4] = { uc.x, uc.y, uc.z, uc.w };
#pragma unroll
            for (int ky = 0; ky < 3; ++ky) {
                const int i = 4 - ky;
#pragma unroll
                for (int kx = 0; kx < 3; ++kx) {
                    const float cf = af[ky * 3 + kx];
#pragma unroll
                    for (int j = 0; j < 4; ++j)
                        e[j] += cf * w[i][4 + j - kx];
                }
            }
            if (crop) {
                float* oe = ob + (size_t)(2 * m) * tstr;
                *(float4*)(oe + y * HW + xc) = make_float4(e[0], e[1], e[2], e[3]);
                *(float4*)(oe + tstr + y * HW + xc) = accn;
            }
        }

        *(float4*)(hnew + y * HSTR + xc) = accn;

        __syncthreads();   // hnew complete; all reads of hold done

        float* tmp = hold; hold = hnew; hnew = tmp;
        acc = accn;
        gc = gn; uc = un;
    }
}

// ---------------- Fallback (round-1 fused, known-correct) --------------------
__global__ __launch_bounds__(256)
void convssm_scan_fused(const float* __restrict__ x_seq,
                        const float* __restrict__ A_k,
                        const float* __restrict__ B_k,
                        float* __restrict__ out)
{
    __shared__ float h0[N][N];
    __shared__ float h1[N][N];
    __shared__ float xs[N][N];

    const int bc = blockIdx.x;
    const int b  = bc >> 5;
    const int c  = bc & 31;
    const int tid = threadIdx.x;
    const int x   = tid & 63;
    const int y0  = (tid >> 6) << 4;

    float a[9], bw[9];
#pragma unroll
    for (int i = 0; i < 9; ++i) { a[i] = A_k[c*9+i]; bw[i] = B_k[c*9+i]; }
#pragma unroll
    for (int r = 0; r < 16; ++r) { h0[y0+r][x] = 0.f; xs[y0+r][x] = 0.f; }

    float (*hold)[N] = h0;
    float (*hnew)[N] = h1;
    const int xm1 = (x + 63) & 63, xm2 = (x + 62) & 63;
    const size_t img = (size_t)HW*HW, tstr = (size_t)NIMG*img;
    const float* xbase = x_seq + ((size_t)b*C_DIM + c)*img;
    float* obase = out + ((size_t)b*C_DIM + c)*img;
    const bool loader = (x < HW);

    for (int t = 0; t < T_STEPS; ++t) {
        if (loader) {
#pragma unroll
            for (int r = 0; r < 16; ++r) {
                int yy = y0 + r;
                if (yy < HW) xs[yy][x] = xbase[(size_t)t*tstr + yy*HW + x];
            }
        }
        __syncthreads();
        const int ym1 = (y0 + N - 1) & 63, ym2 = (y0 + N - 2) & 63;
        float hr1c0 = hold[ym1][x], hr1c1 = hold[ym1][xm1], hr1c2 = hold[ym1][xm2];
        float hr2c0 = hold[ym2][x], hr2c1 = hold[ym2][xm1], hr2c2 = hold[ym2][xm2];
        float sr1c0 = xs[ym1][x], sr1c1 = xs[ym1][xm1], sr1c2 = xs[ym1][xm2];
        float sr2c0 = xs[ym2][x], sr2c1 = xs[ym2][xm1], sr2c2 = xs[ym2][xm2];
#pragma unroll
        for (int r = 0; r < 16; ++r) {
            const int yy = y0 + r;
            float hr0c0 = hold[yy][x], hr0c1 = hold[yy][xm1], hr0c2 = hold[yy][xm2];
            float sr0c0 = xs[yy][x], sr0c1 = xs[yy][xm1], sr0c2 = xs[yy][xm2];
            float v = a[0]*hr0c0 + a[1]*hr0c1 + a[2]*hr0c2
                    + a[3]*hr1c0 + a[4]*hr1c1 + a[5]*hr1c2
                    + a[6]*hr2c0 + a[7]*hr2c1 + a[8]*hr2c2
                    + bw[0]*sr0c0 + bw[1]*sr0c1 + bw[2]*sr0c2
                    + bw[3]*sr1c0 + bw[4]*sr1c1 + bw[5]*sr1c2
                    + bw[6]*sr2c0 + bw[7]*sr2c1 + bw[8]*sr2c2;
            hnew[yy][x] = v;
            if (yy < HW && x < HW) obase[(size_t)t*tstr + yy*HW + x] = v;
            hr2c0=hr1c0; hr2c1=hr1c1; hr2c2=hr1c2;
            hr1c0=hr0c0; hr1c1=hr0c1; hr1c2=hr0c2;
            sr2c0=sr1c0; sr2c1=sr1c1; sr2c2=sr1c2;
            sr1c0=sr0c0; sr1c1=sr0c1; sr1c2=sr0c2;
        }
        __syncthreads();
        float (*tmp)[N] = hold; hold = hnew; hnew = tmp;
    }
}

extern "C" void kernel_launch(void* const* d_in, const int* in_sizes, int n_in,
                              void* d_out, int out_size, void* d_ws, size_t ws_size,
                              hipStream_t stream)
{
    const float* x_seq = (const float*)d_in[0];
    const float* A_k   = (const float*)d_in[1];
    const float* B_k   = (const float*)d_in[2];
    float* out = (float*)d_out;

    const size_t needU = (size_t)NIMG * MH * USZ;             // floats
    const size_t needG = (size_t)NIMG * MH * GSZ;
    const size_t need  = (needU + needG) * sizeof(float);     // ~19 MB

    if (ws_size >= need) {
        float* U = (float*)d_ws;
        float* G = U + needU;
        convssm_pass1d<<<dim3(MH * NIMG), dim3(256), 0, stream>>>(
            x_seq, A_k, B_k, U, G);
        convssm_scan5<<<dim3(NIMG), dim3(1024), 0, stream>>>(
            U, G, A_k, out);
    } else {
        convssm_scan_fused<<<dim3(NIMG), dim3(256), 0, stream>>>(
            x_seq, A_k, B_k, out);
    }
}

// Round 8
// 65.768 us; speedup vs baseline: 1.0016x; 1.0004x over previous
//
#include <hip/hip_runtime.h>

// ConvSSM scan, spatial domain, step-doubled, 1024-thread scan (4 waves/SIMD).
//   h_t = A (*) h_{t-1} + u_t,  u_t = B (*) xpad_t,  (*) = circular conv on 64x64.
// H_m = h_{2m+1}:
//   H_m  = A2 (*) H_{m-1} + G_m,  A2 = A(*)A (5x5),  G_m = A(*)u_{2m} + u_{2m+1}
//   h_2m = A  (*) H_{m-1} + u_{2m}   (even emit, crop region only)
// Pass 1 (2048 blocks, vectorized): U_m = u_{2m} crop 32x32, G_m (36x36) -> d_ws.
// Pass 2 (64 blocks x 1024 thr): 32-step scan, h in LDS dbuf, 1x4 tile/thread,
//   own-row accumulator kept in registers, A/A2 in SGPRs via readfirstlane.

constexpr int T_STEPS = 64;
constexpr int B_DIM   = 2;
constexpr int C_DIM   = 32;
constexpr int HW      = 32;
constexpr int N       = 64;
constexpr int NIMG    = B_DIM * C_DIM;   // 64
constexpr int MH      = T_STEPS / 2;     // 32 scan steps
constexpr int HSTR    = 68;              // LDS row stride (floats)
constexpr int GSZ     = 36 * 36;         // 1296 floats
constexpr int USZ     = HW * HW;         // 1024 floats (cropped u_even)

__device__ __forceinline__ float rfl(float v) {
    return __int_as_float(__builtin_amdgcn_readfirstlane(__float_as_int(v)));
}

// ---------------- Pass 1: U_m (32x32), G_m (36x36) per (m, bc) ---------------
__global__ __launch_bounds__(256)
void convssm_pass1d(const float* __restrict__ x_seq,  // (T,B,C,32,32)
                    const float* __restrict__ A_k,    // (C,3,3)
                    const float* __restrict__ B_k,    // (C,3,3)
                    float* __restrict__ U,            // (NIMG*MH, 32, 32) idx bc*MH+m
                    float* __restrict__ G)            // (NIMG*MH, 36, 36)
{
    __shared__ __align__(16) float xe[32][36];
    __shared__ __align__(16) float xo[32][36];
    __shared__ __align__(16) float ue[34][36];

    const int blk = blockIdx.x;           // m*64 + bc
    const int m   = blk >> 6;
    const int bc  = blk & 63;
    const int c   = bc & 31;
    const int tid = threadIdx.x;

    float a[9], bw[9];
#pragma unroll
    for (int i = 0; i < 9; ++i) { a[i] = A_k[c * 9 + i]; bw[i] = B_k[c * 9 + i]; }

    const float4* xE = (const float4*)(x_seq + ((size_t)(2 * m)     * NIMG + bc) * (HW * HW));
    const float4* xO = (const float4*)(x_seq + ((size_t)(2 * m + 1) * NIMG + bc) * (HW * HW));
    {
        const int y  = tid >> 3;          // 0..31
        const int x4 = (tid & 7) * 4;     // 0,4,...,28
        *(float4*)&xe[y][x4] = xE[tid];
        *(float4*)&xo[y][x4] = xO[tid];
    }
    __syncthreads();

    // ue = B (*) xpad_{2m} over 34x34
    for (int i = tid; i < 34 * 34; i += 256) {
        int y = i / 34, xx = i - y * 34;
        float v = 0.0f;
#pragma unroll
        for (int ky = 0; ky < 3; ++ky) {
            int yy = y - ky;
            if (yy < 0 || yy >= 32) continue;
#pragma unroll
            for (int kx = 0; kx < 3; ++kx) {
                int xs = xx - kx;
                if (xs < 0 || xs >= 32) continue;
                v += bw[ky * 3 + kx] * xe[yy][xs];
            }
        }
        ue[y][xx] = v;
    }
    __syncthreads();

    // store U = crop(ue) as float4
    float* Ug = U + (size_t)(bc * MH + m) * USZ;
    {
        const int y  = tid >> 3;
        const int x4 = (tid & 7) * 4;
        *(float4*)(Ug + y * HW + x4) = *(const float4*)&ue[y][x4];
    }

    // G_m = B (*) xpad_{2m+1} + A (*) ue : support 36x36, stored as float4
    float* Gg = G + (size_t)(bc * MH + m) * GSZ;
    for (int i4 = tid; i4 < 324; i4 += 256) {
        const int y  = i4 / 9;
        const int x0 = (i4 - y * 9) * 4;
        float r[4];
#pragma unroll
        for (int j = 0; j < 4; ++j) {
            const int xx = x0 + j;
            float v = 0.0f;
#pragma unroll
            for (int ky = 0; ky < 3; ++ky) {
#pragma unroll
                for (int kx = 0; kx < 3; ++kx) {
                    int yy = y - ky, xs = xx - kx;
                    if (yy >= 0 && yy < 32 && xs >= 0 && xs < 32)
                        v += bw[ky * 3 + kx] * xo[yy][xs];
                    if (yy >= 0 && yy < 34 && xs >= 0 && xs < 34)
                        v += a[ky * 3 + kx] * ue[yy][xs];
                }
            }
            r[j] = v;
        }
        *(float4*)(Gg + y * 36 + x0) = make_float4(r[0], r[1], r[2], r[3]);
    }
}

// ---------------- Pass 2: 32-step scan, 1024 threads -------------------------
__global__ __launch_bounds__(1024)
void convssm_scan5(const float* __restrict__ U,
                   const float* __restrict__ G,
                   const float* __restrict__ A_k,
                   float* __restrict__ out)          // (T,B,C,32,32)
{
    __shared__ __align__(16) float hbuf[2][N * HSTR];

    const int bc  = blockIdx.x;          // 0..63
    const int c   = bc & 31;
    const int tid = threadIdx.x;
    const int g   = tid & 15;            // col group: cols 4g..4g+3
    const int y   = tid >> 4;            // 0..63: own row
    const int xc  = g * 4;
    const int xlo = (xc + 60) & 63;      // xc-4 mod 64

    // A, A2 -> compute in VALU, park in SGPRs (block-uniform)
    float af[9];
#pragma unroll
    for (int i = 0; i < 9; ++i) af[i] = A_k[c * 9 + i];

    float a2f[25];
#pragma unroll
    for (int p = 0; p < 5; ++p) {
#pragma unroll
        for (int q = 0; q < 5; ++q) {
            float v = 0.0f;
#pragma unroll
            for (int ky = 0; ky < 3; ++ky) {
                int py = p - ky;
                if (py < 0 || py > 2) continue;
#pragma unroll
                for (int kx = 0; kx < 3; ++kx) {
                    int qx = q - kx;
                    if (qx < 0 || qx > 2) continue;
                    v += af[ky * 3 + kx] * af[py * 3 + qx];
                }
            }
            a2f[p * 5 + q] = v;
        }
    }
#pragma unroll
    for (int i = 0; i < 25; ++i) a2f[i] = rfl(a2f[i]);
#pragma unroll
    for (int i = 0; i < 9; ++i)  af[i]  = rfl(af[i]);

    for (int i = tid; i < N * HSTR; i += 1024) hbuf[0][i] = 0.0f;

    const bool cropw = (y < HW);                 // wave-uniform (4 consecutive rows)
    const bool crop  = cropw && (xc < HW);
    const bool gok   = (y < 36) && (xc <= 32);

    const float* Ub = U + (size_t)bc * MH * USZ + y * HW + xc;
    const float* Gb = G + (size_t)bc * MH * GSZ + y * 36 + xc;

    const float4 z4 = make_float4(0.f, 0.f, 0.f, 0.f);
    float4 gc = z4, uc = z4;
    if (gok)  gc = *(const float4*)(Gb);
    if (crop) uc = *(const float4*)(Ub);

    float* hold = &hbuf[0][0];
    float* hnew = &hbuf[1][0];
    float* ob   = out + (size_t)bc * (HW * HW);
    const size_t tstr = (size_t)NIMG * (HW * HW);  // 65536

    float4 acc = z4;   // own row y, cols xc..xc+3 of h_old (starts at 0)

    __syncthreads();

    for (int m = 0; m < MH; ++m) {
        // prefetch next step's G / U
        float4 gn = z4, un = z4;
        if (m + 1 < MH) {
            if (gok)  gn = *(const float4*)(Gb + (size_t)(m + 1) * GSZ);
            if (crop) un = *(const float4*)(Ub + (size_t)(m + 1) * USZ);
        }

        // 5x8 window: rows y-4..y, cols xc-4..xc+3; own row hi-half = acc (regs)
        float w[5][8];
#pragma unroll
        for (int i = 0; i < 5; ++i) {
            const int rr = (y + 60 + i) & 63;
            const float4 lo = *(const float4*)(hold + rr * HSTR + xlo);
            w[i][0] = lo.x; w[i][1] = lo.y; w[i][2] = lo.z; w[i][3] = lo.w;
            if (i < 4) {
                const float4 hi = *(const float4*)(hold + rr * HSTR + xc);
                w[i][4] = hi.x; w[i][5] = hi.y; w[i][6] = hi.z; w[i][7] = hi.w;
            }
        }
        w[4][4] = acc.x; w[4][5] = acc.y; w[4][6] = acc.z; w[4][7] = acc.w;

        // H_new = A2 (*) H_old + G   (1 row x 4 cols)
        float o[4] = { gc.x, gc.y, gc.z, gc.w };
#pragma unroll
        for (int p = 0; p < 5; ++p) {
            const int i = 4 - p;
#pragma unroll
            for (int q = 0; q < 5; ++q) {
                const float cf = a2f[p * 5 + q];
#pragma unroll
                for (int j = 0; j < 4; ++j)
                    o[j] += cf * w[i][4 + j - q];
            }
        }
        const float4 accn = make_float4(o[0], o[1], o[2], o[3]);

        // even emit: h_{2m} = A (*) H_old + u_{2m}
        if (cropw) {
            float e[4] = { uc.x, uc.y, uc.z, uc.w };
#pragma unroll
            for (int ky = 0; ky < 3; ++ky) {
                const int i = 4 - ky;
#pragma unroll
                for (int kx = 0; kx < 3; ++kx) {
                    const float cf = af[ky * 3 + kx];
#pragma unroll
                    for (int j = 0; j < 4; ++j)
                        e[j] += cf * w[i][4 + j - kx];
                }
            }
            if (crop) {
                float* oe = ob + (size_t)(2 * m) * tstr;
                *(float4*)(oe + y * HW + xc) = make_float4(e[0], e[1], e[2], e[3]);
                *(float4*)(oe + tstr + y * HW + xc) = accn;
            }
        }

        *(float4*)(hnew + y * HSTR + xc) = accn;

        __syncthreads();   // hnew complete; all reads of hold done

        float* tmp = hold; hold = hnew; hnew = tmp;
        acc = accn;
        gc = gn; uc = un;
    }
}

// ---------------- Fallback (round-1 fused, known-correct) --------------------
__global__ __launch_bounds__(256)
void convssm_scan_fused(const float* __restrict__ x_seq,
                        const float* __restrict__ A_k,
                        const float* __restrict__ B_k,
                        float* __restrict__ out)
{
    __shared__ float h0[N][N];
    __shared__ float h1[N][N];
    __shared__ float xs[N][N];

    const int bc = blockIdx.x;
    const int b  = bc >> 5;
    const int c  = bc & 31;
    const int tid = threadIdx.x;
    const int x   = tid & 63;
    const int y0  = (tid >> 6) << 4;

    float a[9], bw[9];
#pragma unroll
    for (int i = 0; i < 9; ++i) { a[i] = A_k[c*9+i]; bw[i] = B_k[c*9+i]; }
#pragma unroll
    for (int r = 0; r < 16; ++r) { h0[y0+r][x] = 0.f; xs[y0+r][x] = 0.f; }

    float (*hold)[N] = h0;
    float (*hnew)[N] = h1;
    const int xm1 = (x + 63) & 63, xm2 = (x + 62) & 63;
    const size_t img = (size_t)HW*HW, tstr = (size_t)NIMG*img;
    const float* xbase = x_seq + ((size_t)b*C_DIM + c)*img;
    float* obase = out + ((size_t)b*C_DIM + c)*img;
    const bool loader = (x < HW);

    for (int t = 0; t < T_STEPS; ++t) {
        if (loader) {
#pragma unroll
            for (int r = 0; r < 16; ++r) {
                int yy = y0 + r;
                if (yy < HW) xs[yy][x] = xbase[(size_t)t*tstr + yy*HW + x];
            }
        }
        __syncthreads();
        const int ym1 = (y0 + N - 1) & 63, ym2 = (y0 + N - 2) & 63;
        float hr1c0 = hold[ym1][x], hr1c1 = hold[ym1][xm1], hr1c2 = hold[ym1][xm2];
        float hr2c0 = hold[ym2][x], hr2c1 = hold[ym2][xm1], hr2c2 = hold[ym2][xm2];
        float sr1c0 = xs[ym1][x], sr1c1 = xs[ym1][xm1], sr1c2 = xs[ym1][xm2];
        float sr2c0 = xs[ym2][x], sr2c1 = xs[ym2][xm1], sr2c2 = xs[ym2][xm2];
#pragma unroll
        for (int r = 0; r < 16; ++r) {
            const int yy = y0 + r;
            float hr0c0 = hold[yy][x], hr0c1 = hold[yy][xm1], hr0c2 = hold[yy][xm2];
            float sr0c0 = xs[yy][x], sr0c1 = xs[yy][xm1], sr0c2 = xs[yy][xm2];
            float v = a[0]*hr0c0 + a[1]*hr0c1 + a[2]*hr0c2
                    + a[3]*hr1c0 + a[4]*hr1c1 + a[5]*hr1c2
                    + a[6]*hr2c0 + a[7]*hr2c1 + a[8]*hr2c2
                    + bw[0]*sr0c0 + bw[1]*sr0c1 + bw[2]*sr0c2
                    + bw[3]*sr1c0 + bw[4]*sr1c1 + bw[5]*sr1c2
                    + bw[6]*sr2c0 + bw[7]*sr2c1 + bw[8]*sr2c2;
            hnew[yy][x] = v;
            if (yy < HW && x < HW) obase[(size_t)t*tstr + yy*HW + x] = v;
            hr2c0=hr1c0; hr2c1=hr1c1; hr2c2=hr1c2;
            hr1c0=hr0c0; hr1c1=hr0c1; hr1c2=hr0c2;
            sr2c0=sr1c0; sr2c1=sr1c1; sr2c2=sr1c2;
            sr1c0=sr0c0; sr1c1=sr0c1; sr1c2=sr0c2;
        }
        __syncthreads();
        float (*tmp)[N] = hold; hold = hnew; hnew = tmp;
    }
}

extern "C" void kernel_launch(void* const* d_in, const int* in_sizes, int n_in,
                              void* d_out, int out_size, void* d_ws, size_t ws_size,
                              hipStream_t stream)
{
    const float* x_seq = (const float*)d_in[0];
    const float* A_k   = (const float*)d_in[1];
    const float* B_k   = (const float*)d_in[2];
    float* out = (float*)d_out;

    const size_t needU = (size_t)NIMG * MH * USZ;             // floats
    const size_t needG = (size_t)NIMG * MH * GSZ;
    const size_t need  = (needU + needG) * sizeof(float);     // ~19 MB

    if (ws_size >= need) {
        float* U = (float*)d_ws;
        float* G = U + needU;
        convssm_pass1d<<<dim3(MH * NIMG), dim3(256), 0, stream>>>(
            x_seq, A_k, B_k, U, G);
        convssm_scan5<<<dim3(NIMG), dim3(1024), 0, stream>>>(
            U, G, A_k, out);
    } else {
        convssm_scan_fused<<<dim3(NIMG), dim3(256), 0, stream>>>(
            x_seq, A_k, B_k, out);
    }
}

// Round 9
// 64.630 us; speedup vs baseline: 1.0192x; 1.0176x over previous
//
#include <hip/hip_runtime.h>

// ConvSSM scan, spatial domain, step-doubled, 1024-thread scan (4 waves/SIMD),
// DPP row_ror:1 supplies the column halo (cuts LDS reads ~45%).
//   h_t = A (*) h_{t-1} + u_t,  u_t = B (*) xpad_t,  (*) = circular conv on 64x64.
// H_m = h_{2m+1}:
//   H_m  = A2 (*) H_{m-1} + G_m,  A2 = A(*)A (5x5),  G_m = A(*)u_{2m} + u_{2m+1}
//   h_2m = A  (*) H_{m-1} + u_{2m}   (even emit, crop region only)
// Pass 1 (2048 blocks): U_m = u_{2m} crop 32x32, G_m (36x36) -> d_ws.
// Pass 2 (64 blocks x 1024 thr): 32-step scan, h in LDS dbuf, 1x4 tile/thread.
//   Window cols xc-4..xc-1 come from lane g-1 via DPP (lane = (y%4)*16 + g, so
//   the 16 col-groups of one image row fill exactly one 16-lane DPP row; the
//   rotate also implements the mod-64 column wrap at g=0).

constexpr int T_STEPS = 64;
constexpr int B_DIM   = 2;
constexpr int C_DIM   = 32;
constexpr int HW      = 32;
constexpr int N       = 64;
constexpr int NIMG    = B_DIM * C_DIM;   // 64
constexpr int MH      = T_STEPS / 2;     // 32 scan steps
constexpr int HSTR    = 68;              // LDS row stride (floats)
constexpr int GSZ     = 36 * 36;         // 1296 floats
constexpr int USZ     = HW * HW;         // 1024 floats (cropped u_even)

__device__ __forceinline__ float rfl(float v) {
    return __int_as_float(__builtin_amdgcn_readfirstlane(__float_as_int(v)));
}

// dst lane g receives src lane (g-1) & 15 within each 16-lane DPP row
// (ROW_ROR0 = 0x120; row_ror:1 = 0x121).
__device__ __forceinline__ float ror1(float x) {
    return __int_as_float(__builtin_amdgcn_update_dpp(
        0, __float_as_int(x), 0x121, 0xF, 0xF, false));
}

// ---------------- Pass 1: U_m (32x32), G_m (36x36) per (m, bc) ---------------
__global__ __launch_bounds__(256)
void convssm_pass1d(const float* __restrict__ x_seq,  // (T,B,C,32,32)
                    const float* __restrict__ A_k,    // (C,3,3)
                    const float* __restrict__ B_k,    // (C,3,3)
                    float* __restrict__ U,            // (NIMG*MH, 32, 32) idx bc*MH+m
                    float* __restrict__ G)            // (NIMG*MH, 36, 36)
{
    __shared__ __align__(16) float xe[32][36];
    __shared__ __align__(16) float xo[32][36];
    __shared__ __align__(16) float ue[34][36];

    const int blk = blockIdx.x;           // m*64 + bc
    const int m   = blk >> 6;
    const int bc  = blk & 63;
    const int c   = bc & 31;
    const int tid = threadIdx.x;

    float a[9], bw[9];
#pragma unroll
    for (int i = 0; i < 9; ++i) { a[i] = A_k[c * 9 + i]; bw[i] = B_k[c * 9 + i]; }

    const float4* xE = (const float4*)(x_seq + ((size_t)(2 * m)     * NIMG + bc) * (HW * HW));
    const float4* xO = (const float4*)(x_seq + ((size_t)(2 * m + 1) * NIMG + bc) * (HW * HW));
    {
        const int y  = tid >> 3;          // 0..31
        const int x4 = (tid & 7) * 4;     // 0,4,...,28
        *(float4*)&xe[y][x4] = xE[tid];
        *(float4*)&xo[y][x4] = xO[tid];
    }
    __syncthreads();

    // ue = B (*) xpad_{2m} over 34x34
    for (int i = tid; i < 34 * 34; i += 256) {
        int y = i / 34, xx = i - y * 34;
        float v = 0.0f;
#pragma unroll
        for (int ky = 0; ky < 3; ++ky) {
            int yy = y - ky;
            if (yy < 0 || yy >= 32) continue;
#pragma unroll
            for (int kx = 0; kx < 3; ++kx) {
                int xs = xx - kx;
                if (xs < 0 || xs >= 32) continue;
                v += bw[ky * 3 + kx] * xe[yy][xs];
            }
        }
        ue[y][xx] = v;
    }
    __syncthreads();

    // store U = crop(ue) as float4
    float* Ug = U + (size_t)(bc * MH + m) * USZ;
    {
        const int y  = tid >> 3;
        const int x4 = (tid & 7) * 4;
        *(float4*)(Ug + y * HW + x4) = *(const float4*)&ue[y][x4];
    }

    // G_m = B (*) xpad_{2m+1} + A (*) ue : support 36x36, stored as float4
    float* Gg = G + (size_t)(bc * MH + m) * GSZ;
    for (int i4 = tid; i4 < 324; i4 += 256) {
        const int y  = i4 / 9;
        const int x0 = (i4 - y * 9) * 4;
        float r[4];
#pragma unroll
        for (int j = 0; j < 4; ++j) {
            const int xx = x0 + j;
            float v = 0.0f;
#pragma unroll
            for (int ky = 0; ky < 3; ++ky) {
#pragma unroll
                for (int kx = 0; kx < 3; ++kx) {
                    int yy = y - ky, xs = xx - kx;
                    if (yy >= 0 && yy < 32 && xs >= 0 && xs < 32)
                        v += bw[ky * 3 + kx] * xo[yy][xs];
                    if (yy >= 0 && yy < 34 && xs >= 0 && xs < 34)
                        v += a[ky * 3 + kx] * ue[yy][xs];
                }
            }
            r[j] = v;
        }
        *(float4*)(Gg + y * 36 + x0) = make_float4(r[0], r[1], r[2], r[3]);
    }
}

// ---------------- Pass 2: 32-step scan, 1024 threads, DPP halo ---------------
__global__ __launch_bounds__(1024)
void convssm_scan6(const float* __restrict__ U,
                   const float* __restrict__ G,
                   const float* __restrict__ A_k,
                   float* __restrict__ out)          // (T,B,C,32,32)
{
    __shared__ __align__(16) float hbuf[2][N * HSTR];

    const int bc  = blockIdx.x;          // 0..63
    const int c   = bc & 31;
    const int tid = threadIdx.x;
    const int g   = tid & 15;            // col group: cols 4g..4g+3
    const int y   = tid >> 4;            // 0..63: own row
    const int xc  = g * 4;

    // A, A2 -> compute in VALU, park in SGPRs (block-uniform)
    float af[9];
#pragma unroll
    for (int i = 0; i < 9; ++i) af[i] = A_k[c * 9 + i];

    float a2f[25];
#pragma unroll
    for (int p = 0; p < 5; ++p) {
#pragma unroll
        for (int q = 0; q < 5; ++q) {
            float v = 0.0f;
#pragma unroll
            for (int ky = 0; ky < 3; ++ky) {
                int py = p - ky;
                if (py < 0 || py > 2) continue;
#pragma unroll
                for (int kx = 0; kx < 3; ++kx) {
                    int qx = q - kx;
                    if (qx < 0 || qx > 2) continue;
                    v += af[ky * 3 + kx] * af[py * 3 + qx];
                }
            }
            a2f[p * 5 + q] = v;
        }
    }
#pragma unroll
    for (int i = 0; i < 25; ++i) a2f[i] = rfl(a2f[i]);
#pragma unroll
    for (int i = 0; i < 9; ++i)  af[i]  = rfl(af[i]);

    for (int i = tid; i < N * HSTR; i += 1024) hbuf[0][i] = 0.0f;

    const bool cropw = (y < HW);                 // wave-uniform (4 consecutive rows)
    const bool crop  = cropw && (xc < HW);
    const bool gok   = (y < 36) && (xc <= 32);

    const float* Ub = U + (size_t)bc * MH * USZ + y * HW + xc;
    const float* Gb = G + (size_t)bc * MH * GSZ + y * 36 + xc;

    const float4 z4 = make_float4(0.f, 0.f, 0.f, 0.f);
    float4 gc = z4, uc = z4;
    if (gok)  gc = *(const float4*)(Gb);
    if (crop) uc = *(const float4*)(Ub);

    float* hold = &hbuf[0][0];
    float* hnew = &hbuf[1][0];
    float* ob   = out + (size_t)bc * (HW * HW);
    const size_t tstr = (size_t)NIMG * (HW * HW);  // 65536

    float4 acc = z4;   // own row y, cols xc..xc+3 of h_old (starts at 0)

    __syncthreads();

    for (int m = 0; m < MH; ++m) {
        // prefetch next step's G / U
        float4 gn = z4, un = z4;
        if (m + 1 < MH) {
            if (gok)  gn = *(const float4*)(Gb + (size_t)(m + 1) * GSZ);
            if (crop) un = *(const float4*)(Ub + (size_t)(m + 1) * USZ);
        }

        // 5x8 window, rows y-4..y, cols xc-4..xc+3.
        // hi (cols xc..xc+3): rows y-4..y-1 from LDS, row y from acc regs.
        // lo (cols xc-4..xc-1): DPP row_ror:1 of lane g-1's hi (wrap incl.)
        float4 hi[4];
#pragma unroll
        for (int i = 0; i < 4; ++i) {
            const int rr = (y + 60 + i) & 63;
            hi[i] = *(const float4*)(hold + rr * HSTR + xc);
        }

        float w[5][8];
#pragma unroll
        for (int i = 0; i < 4; ++i) {
            w[i][4] = hi[i].x; w[i][5] = hi[i].y; w[i][6] = hi[i].z; w[i][7] = hi[i].w;
            w[i][0] = ror1(hi[i].x); w[i][1] = ror1(hi[i].y);
            w[i][2] = ror1(hi[i].z); w[i][3] = ror1(hi[i].w);
        }
        w[4][4] = acc.x; w[4][5] = acc.y; w[4][6] = acc.z; w[4][7] = acc.w;
        w[4][0] = ror1(acc.x); w[4][1] = ror1(acc.y);
        w[4][2] = ror1(acc.z); w[4][3] = ror1(acc.w);

        // H_new = A2 (*) H_old + G   (1 row x 4 cols)
        float o[4] = { gc.x, gc.y, gc.z, gc.w };
#pragma unroll
        for (int p = 0; p < 5; ++p) {
            const int i = 4 - p;
#pragma unroll
            for (int q = 0; q < 5; ++q) {
                const float cf = a2f[p * 5 + q];
#pragma unroll
                for (int j = 0; j < 4; ++j)
                    o[j] += cf * w[i][4 + j - q];
            }
        }
        const float4 accn = make_float4(o[0], o[1], o[2], o[3]);

        // even emit: h_{2m} = A (*) H_old + u_{2m}
        if (cropw) {
            float e[4] = { uc.x, uc.y, uc.z, uc.w };
#pragma unroll
            for (int ky = 0; ky < 3; ++ky) {
                const int i = 4 - ky;
#pragma unroll
                for (int kx = 0; kx < 3; ++kx) {
                    const float cf = af[ky * 3 + kx];
#pragma unroll
                    for (int j = 0; j < 4; ++j)
                        e[j] += cf * w[i][4 + j - kx];
                }
            }
            if (crop) {
                float* oe = ob + (size_t)(2 * m) * tstr;
                *(float4*)(oe + y * HW + xc) = make_float4(e[0], e[1], e[2], e[3]);
                *(float4*)(oe + tstr + y * HW + xc) = accn;
            }
        }

        *(float4*)(hnew + y * HSTR + xc) = accn;

        __syncthreads();   // hnew complete; all reads of hold done

        float* tmp = hold; hold = hnew; hnew = tmp;
        acc = accn;
        gc = gn; uc = un;
    }
}

// ---------------- Fallback (round-1 fused, known-correct) --------------------
__global__ __launch_bounds__(256)
void convssm_scan_fused(const float* __restrict__ x_seq,
                        const float* __restrict__ A_k,
                        const float* __restrict__ B_k,
                        float* __restrict__ out)
{
    __shared__ float h0[N][N];
    __shared__ float h1[N][N];
    __shared__ float xs[N][N];

    const int bc = blockIdx.x;
    const int b  = bc >> 5;
    const int c  = bc & 31;
    const int tid = threadIdx.x;
    const int x   = tid & 63;
    const int y0  = (tid >> 6) << 4;

    float a[9], bw[9];
#pragma unroll
    for (int i = 0; i < 9; ++i) { a[i] = A_k[c*9+i]; bw[i] = B_k[c*9+i]; }
#pragma unroll
    for (int r = 0; r < 16; ++r) { h0[y0+r][x] = 0.f; xs[y0+r][x] = 0.f; }

    float (*hold)[N] = h0;
    float (*hnew)[N] = h1;
    const int xm1 = (x + 63) & 63, xm2 = (x + 62) & 63;
    const size_t img = (size_t)HW*HW, tstr = (size_t)NIMG*img;
    const float* xbase = x_seq + ((size_t)b*C_DIM + c)*img;
    float* obase = out + ((size_t)b*C_DIM + c)*img;
    const bool loader = (x < HW);

    for (int t = 0; t < T_STEPS; ++t) {
        if (loader) {
#pragma unroll
            for (int r = 0; r < 16; ++r) {
                int yy = y0 + r;
                if (yy < HW) xs[yy][x] = xbase[(size_t)t*tstr + yy*HW + x];
            }
        }
        __syncthreads();
        const int ym1 = (y0 + N - 1) & 63, ym2 = (y0 + N - 2) & 63;
        float hr1c0 = hold[ym1][x], hr1c1 = hold[ym1][xm1], hr1c2 = hold[ym1][xm2];
        float hr2c0 = hold[ym2][x], hr2c1 = hold[ym2][xm1], hr2c2 = hold[ym2][xm2];
        float sr1c0 = xs[ym1][x], sr1c1 = xs[ym1][xm1], sr1c2 = xs[ym1][xm2];
        float sr2c0 = xs[ym2][x], sr2c1 = xs[ym2][xm1], sr2c2 = xs[ym2][xm2];
#pragma unroll
        for (int r = 0; r < 16; ++r) {
            const int yy = y0 + r;
            float hr0c0 = hold[yy][x], hr0c1 = hold[yy][xm1], hr0c2 = hold[yy][xm2];
            float sr0c0 = xs[yy][x], sr0c1 = xs[yy][xm1], sr0c2 = xs[yy][xm2];
            float v = a[0]*hr0c0 + a[1]*hr0c1 + a[2]*hr0c2
                    + a[3]*hr1c0 + a[4]*hr1c1 + a[5]*hr1c2
                    + a[6]*hr2c0 + a[7]*hr2c1 + a[8]*hr2c2
                    + bw[0]*sr0c0 + bw[1]*sr0c1 + bw[2]*sr0c2
                    + bw[3]*sr1c0 + bw[4]*sr1c1 + bw[5]*sr1c2
                    + bw[6]*sr2c0 + bw[7]*sr2c1 + bw[8]*sr2c2;
            hnew[yy][x] = v;
            if (yy < HW && x < HW) obase[(size_t)t*tstr + yy*HW + x] = v;
            hr2c0=hr1c0; hr2c1=hr1c1; hr2c2=hr1c2;
            hr1c0=hr0c0; hr1c1=hr0c1; hr1c2=hr0c2;
            sr2c0=sr1c0; sr2c1=sr1c1; sr2c2=sr1c2;
            sr1c0=sr0c0; sr1c1=sr0c1; sr1c2=sr0c2;
        }
        __syncthreads();
        float (*tmp)[N] = hold; hold = hnew; hnew = tmp;
    }
}

extern "C" void kernel_launch(void* const* d_in, const int* in_sizes, int n_in,
                              void* d_out, int out_size, void* d_ws, size_t ws_size,
                              hipStream_t stream)
{
    const float* x_seq = (const float*)d_in[0];
    const float* A_k   = (const float*)d_in[1];
    const float* B_k   = (const float*)d_in[2];
    float* out = (float*)d_out;

    const size_t needU = (size_t)NIMG * MH * USZ;             // floats
    const size_t needG = (size_t)NIMG * MH * GSZ;
    const size_t need  = (needU + needG) * sizeof(float);     // ~19 MB

    if (ws_size >= need) {
        float* U = (float*)d_ws;
        float* G = U + needU;
        convssm_pass1d<<<dim3(MH * NIMG), dim3(256), 0, stream>>>(
            x_seq, A_k, B_k, U, G);
        convssm_scan6<<<dim3(NIMG), dim3(1024), 0, stream>>>(
            U, G, A_k, out);
    } else {
        convssm_scan_fused<<<dim3(NIMG), dim3(256), 0, stream>>>(
            x_seq, A_k, B_k, out);
    }
}